// Round 1
// baseline (524.288 us; speedup 1.0000x reference)
//
#include <hip/hip_runtime.h>
#include <hip/hip_bf16.h>

// GNN link predictor: 2x SAGEConv(mean) + dot-product decode.
// Pipeline:
//   1. build CSR (dst -> list of src) + inv_deg
//   2. mean1 = inv_deg * agg(x)                       [N x 64]
//   3. h = relu(mean1 @ W_l1 + x @ W_r1 + b1)         [N x 128]
//   4. p = h @ W_l2 ; zb = h @ W_r2 + b2              [N x 64] each
//   5. z = inv_deg * agg(p) + zb   (in-place into zb) [N x 64]
//   6. out[k] = dot(z[a_k], z[b_k])                   [P]

__global__ __launch_bounds__(256) void k_count(const int* __restrict__ dst, int E,
                                               int* __restrict__ deg) {
    int e = blockIdx.x * 256 + threadIdx.x;
    if (e < E) atomicAdd(&deg[dst[e]], 1);
}

__global__ __launch_bounds__(1024) void k_scan(const int* __restrict__ deg, int n,
                                               int* __restrict__ off,
                                               float* __restrict__ inv_deg) {
    __shared__ int ws[16];
    __shared__ int s_carry;
    const int t = threadIdx.x;
    const int lane = t & 63, w = t >> 6;
    if (t == 0) s_carry = 0;
    __syncthreads();
    for (int base = 0; base < n; base += 1024) {
        int i = base + t;
        int v = (i < n) ? deg[i] : 0;
        int x = v;
#pragma unroll
        for (int d = 1; d < 64; d <<= 1) {
            int y = __shfl_up(x, d);
            if (lane >= d) x += y;
        }
        if (lane == 63) ws[w] = x;
        __syncthreads();
        int carry = s_carry;
        if (w == 0 && lane < 16) {
            int s = ws[lane];
#pragma unroll
            for (int d = 1; d < 16; d <<= 1) {
                int y = __shfl_up(s, d);
                if (lane >= d) s += y;
            }
            ws[lane] = s;
        }
        __syncthreads();
        int wexcl = (w == 0) ? 0 : ws[w - 1];
        if (i < n) {
            off[i] = carry + wexcl + x - v;
            inv_deg[i] = 1.0f / (float)(v > 0 ? v : 1);
        }
        int total = ws[15];
        __syncthreads();
        if (t == 0) s_carry = carry + total;
    }
    if (t == 0) off[n] = s_carry;
}

__global__ __launch_bounds__(256) void k_fill(const int* __restrict__ ei, int E,
                                              const int* __restrict__ off,
                                              int* __restrict__ cur,
                                              int* __restrict__ csr) {
    int e = blockIdx.x * 256 + threadIdx.x;
    if (e < E) {
        int s = ei[e];
        int d = ei[E + e];
        int pos = atomicAdd(&cur[d], 1);
        csr[off[d] + pos] = s;
    }
}

// one 64-lane wave per node; lane = channel (64 channels)
__global__ __launch_bounds__(256) void k_agg(const float* __restrict__ feat,
                                             const int* __restrict__ off,
                                             const int* __restrict__ csr,
                                             const float* __restrict__ inv_deg,
                                             float* __restrict__ outp,
                                             const float* __restrict__ addend,
                                             int n) {
    int node = blockIdx.x * 4 + (threadIdx.x >> 6);
    int lane = threadIdx.x & 63;
    if (node >= n) return;
    int j0 = off[node], j1 = off[node + 1];
    float acc = 0.f;
    int j = j0;
    for (; j + 4 <= j1; j += 4) {
        int s0 = csr[j], s1 = csr[j + 1], s2 = csr[j + 2], s3 = csr[j + 3];
        float a = feat[(size_t)s0 * 64 + lane];
        float b = feat[(size_t)s1 * 64 + lane];
        float c = feat[(size_t)s2 * 64 + lane];
        float d = feat[(size_t)s3 * 64 + lane];
        acc += a; acc += b; acc += c; acc += d;
    }
    for (; j < j1; ++j) acc += feat[(size_t)csr[j] * 64 + lane];
    float val = acc * inv_deg[node];
    size_t idx = (size_t)node * 64 + lane;
    if (addend) val += addend[idx];
    outp[idx] = val;
}

// h = relu([mean1 | x] @ [W_l1 ; W_r1] + b1)   M x 128, K = 64+64
__global__ __launch_bounds__(256) void k_gemm1(const float* __restrict__ mean1,
                                               const float* __restrict__ x,
                                               const float* __restrict__ Wl,
                                               const float* __restrict__ Wr,
                                               const float* __restrict__ b1,
                                               float* __restrict__ h, int M) {
    __shared__ float As[16][68];
    __shared__ float Ws[16][128];
    const int t = threadIdx.x;
    const int row0 = blockIdx.x * 64;
    const int tm = t & 15, tn = t >> 4;
    float acc[4][8];
#pragma unroll
    for (int i = 0; i < 4; i++)
#pragma unroll
        for (int j = 0; j < 8; j++) acc[i][j] = 0.f;

    const int ar = row0 + (t >> 2);
    const int ak = (t & 3) * 4;
    for (int kk = 0; kk < 8; ++kk) {
        float4 av = make_float4(0.f, 0.f, 0.f, 0.f);
        int kg = kk * 16 + ak;
        if (ar < M) {
            const float* sp = (kg < 64) ? (mean1 + (size_t)ar * 64 + kg)
                                        : (x + (size_t)ar * 64 + (kg - 64));
            av = *(const float4*)sp;
        }
        int k0 = kk * 16 + (t >> 5), j0 = (t & 31) * 4;
        int k1 = k0 + 8;
        float4 wv0 = *(const float4*)((k0 < 64) ? (Wl + k0 * 128 + j0)
                                                : (Wr + (k0 - 64) * 128 + j0));
        float4 wv1 = *(const float4*)((k1 < 64) ? (Wl + k1 * 128 + j0)
                                                : (Wr + (k1 - 64) * 128 + j0));
        __syncthreads();
        int lr = t >> 2;
        As[ak + 0][lr] = av.x; As[ak + 1][lr] = av.y;
        As[ak + 2][lr] = av.z; As[ak + 3][lr] = av.w;
        *(float4*)&Ws[t >> 5][j0] = wv0;
        *(float4*)&Ws[(t >> 5) + 8][j0] = wv1;
        __syncthreads();
#pragma unroll
        for (int k = 0; k < 16; ++k) {
            float4 a4 = *(const float4*)&As[k][tm * 4];
            float4 w0 = *(const float4*)&Ws[k][tn * 8];
            float4 w1 = *(const float4*)&Ws[k][tn * 8 + 4];
            float a[4] = {a4.x, a4.y, a4.z, a4.w};
            float wv[8] = {w0.x, w0.y, w0.z, w0.w, w1.x, w1.y, w1.z, w1.w};
#pragma unroll
            for (int i = 0; i < 4; i++)
#pragma unroll
                for (int j = 0; j < 8; j++) acc[i][j] += a[i] * wv[j];
        }
    }
    float4 bv0 = *(const float4*)&b1[tn * 8];
    float4 bv1 = *(const float4*)&b1[tn * 8 + 4];
    float bb[8] = {bv0.x, bv0.y, bv0.z, bv0.w, bv1.x, bv1.y, bv1.z, bv1.w};
#pragma unroll
    for (int i = 0; i < 4; i++) {
        int r = row0 + tm * 4 + i;
        if (r < M) {
            float4 o0, o1;
            o0.x = fmaxf(acc[i][0] + bb[0], 0.f);
            o0.y = fmaxf(acc[i][1] + bb[1], 0.f);
            o0.z = fmaxf(acc[i][2] + bb[2], 0.f);
            o0.w = fmaxf(acc[i][3] + bb[3], 0.f);
            o1.x = fmaxf(acc[i][4] + bb[4], 0.f);
            o1.y = fmaxf(acc[i][5] + bb[5], 0.f);
            o1.z = fmaxf(acc[i][6] + bb[6], 0.f);
            o1.w = fmaxf(acc[i][7] + bb[7], 0.f);
            *(float4*)&h[(size_t)r * 128 + tn * 8] = o0;
            *(float4*)&h[(size_t)r * 128 + tn * 8 + 4] = o1;
        }
    }
}

// p = h @ W_l2 (cols 0..63) ; zb = h @ W_r2 + b2 (cols 64..127)   K=128
__global__ __launch_bounds__(256) void k_gemm2(const float* __restrict__ h,
                                               const float* __restrict__ Wl,
                                               const float* __restrict__ Wr,
                                               const float* __restrict__ b2,
                                               float* __restrict__ p,
                                               float* __restrict__ zb, int M) {
    __shared__ float As[16][68];
    __shared__ float Ws[16][128];
    const int t = threadIdx.x;
    const int row0 = blockIdx.x * 64;
    const int tm = t & 15, tn = t >> 4;
    float acc[4][8];
#pragma unroll
    for (int i = 0; i < 4; i++)
#pragma unroll
        for (int j = 0; j < 8; j++) acc[i][j] = 0.f;

    const int ar = row0 + (t >> 2);
    const int ak = (t & 3) * 4;
    for (int kk = 0; kk < 8; ++kk) {
        float4 av = make_float4(0.f, 0.f, 0.f, 0.f);
        int kg = kk * 16 + ak;
        if (ar < M) av = *(const float4*)(h + (size_t)ar * 128 + kg);
        int k0 = kk * 16 + (t >> 5), j0 = (t & 31) * 4;
        int k1 = k0 + 8;
        float4 wv0 = *(const float4*)((j0 < 64) ? (Wl + k0 * 64 + j0)
                                                : (Wr + k0 * 64 + (j0 - 64)));
        float4 wv1 = *(const float4*)((j0 < 64) ? (Wl + k1 * 64 + j0)
                                                : (Wr + k1 * 64 + (j0 - 64)));
        __syncthreads();
        int lr = t >> 2;
        As[ak + 0][lr] = av.x; As[ak + 1][lr] = av.y;
        As[ak + 2][lr] = av.z; As[ak + 3][lr] = av.w;
        *(float4*)&Ws[t >> 5][j0] = wv0;
        *(float4*)&Ws[(t >> 5) + 8][j0] = wv1;
        __syncthreads();
#pragma unroll
        for (int k = 0; k < 16; ++k) {
            float4 a4 = *(const float4*)&As[k][tm * 4];
            float4 w0 = *(const float4*)&Ws[k][tn * 8];
            float4 w1 = *(const float4*)&Ws[k][tn * 8 + 4];
            float a[4] = {a4.x, a4.y, a4.z, a4.w};
            float wv[8] = {w0.x, w0.y, w0.z, w0.w, w1.x, w1.y, w1.z, w1.w};
#pragma unroll
            for (int i = 0; i < 4; i++)
#pragma unroll
                for (int j = 0; j < 8; j++) acc[i][j] += a[i] * wv[j];
        }
    }
    int c = tn * 8;
    if (c < 64) {
#pragma unroll
        for (int i = 0; i < 4; i++) {
            int r = row0 + tm * 4 + i;
            if (r < M) {
                *(float4*)&p[(size_t)r * 64 + c] =
                    make_float4(acc[i][0], acc[i][1], acc[i][2], acc[i][3]);
                *(float4*)&p[(size_t)r * 64 + c + 4] =
                    make_float4(acc[i][4], acc[i][5], acc[i][6], acc[i][7]);
            }
        }
    } else {
        int cc = c - 64;
        float4 bv0 = *(const float4*)&b2[cc];
        float4 bv1 = *(const float4*)&b2[cc + 4];
#pragma unroll
        for (int i = 0; i < 4; i++) {
            int r = row0 + tm * 4 + i;
            if (r < M) {
                *(float4*)&zb[(size_t)r * 64 + cc] =
                    make_float4(acc[i][0] + bv0.x, acc[i][1] + bv0.y,
                                acc[i][2] + bv0.z, acc[i][3] + bv0.w);
                *(float4*)&zb[(size_t)r * 64 + cc + 4] =
                    make_float4(acc[i][4] + bv1.x, acc[i][5] + bv1.y,
                                acc[i][6] + bv1.z, acc[i][7] + bv1.w);
            }
        }
    }
}

// 16 lanes per pair; float4 loads; shfl_xor reduce
__global__ __launch_bounds__(256) void k_decode(const float* __restrict__ z,
                                                const int* __restrict__ eli,
                                                float* __restrict__ out, int P) {
    int t = threadIdx.x;
    int g = blockIdx.x * 16 + (t >> 4);
    int l = t & 15;
    if (g >= P) return;
    int a = eli[g];
    int b = eli[P + g];
    float4 va = *(const float4*)(z + (size_t)a * 64 + l * 4);
    float4 vb = *(const float4*)(z + (size_t)b * 64 + l * 4);
    float s = va.x * vb.x + va.y * vb.y + va.z * vb.z + va.w * vb.w;
    s += __shfl_xor(s, 1);
    s += __shfl_xor(s, 2);
    s += __shfl_xor(s, 4);
    s += __shfl_xor(s, 8);
    if (l == 0) out[g] = s;
}

extern "C" void kernel_launch(void* const* d_in, const int* in_sizes, int n_in,
                              void* d_out, int out_size, void* d_ws, size_t ws_size,
                              hipStream_t stream) {
    const float* x   = (const float*)d_in[0];
    const float* Wl1 = (const float*)d_in[1];
    const float* Wr1 = (const float*)d_in[2];
    const float* b1  = (const float*)d_in[3];
    const float* Wl2 = (const float*)d_in[4];
    const float* Wr2 = (const float*)d_in[5];
    const float* b2  = (const float*)d_in[6];
    const int* ei  = (const int*)d_in[7];
    const int* eli = (const int*)d_in[8];
    const int N = in_sizes[0] / 64;
    const int E = in_sizes[7] / 2;
    const int P = in_sizes[8] / 2;
    float* out = (float*)d_out;

    char* w = (char*)d_ws;
    auto alloc = [&](size_t bytes) {
        char* pp = w;
        w += (bytes + 255) & ~(size_t)255;
        return pp;
    };
    int*   deg   = (int*)alloc((size_t)N * 4);
    int*   cur   = (int*)alloc((size_t)N * 4);
    int*   off   = (int*)alloc(((size_t)N + 1) * 4);
    float* inv   = (float*)alloc((size_t)N * 4);
    int*   csr   = (int*)alloc((size_t)E * 4);
    float* mean1 = (float*)alloc((size_t)N * 64 * 4);  // reused as p
    float* h     = (float*)alloc((size_t)N * 128 * 4);
    float* zb    = (float*)alloc((size_t)N * 64 * 4);  // becomes z in-place

    hipMemsetAsync(deg, 0, (size_t)N * 4, stream);
    hipMemsetAsync(cur, 0, (size_t)N * 4, stream);

    k_count<<<(E + 255) / 256, 256, 0, stream>>>(ei + E, E, deg);
    k_scan<<<1, 1024, 0, stream>>>(deg, N, off, inv);
    k_fill<<<(E + 255) / 256, 256, 0, stream>>>(ei, E, off, cur, csr);

    k_agg<<<(N + 3) / 4, 256, 0, stream>>>(x, off, csr, inv, mean1, nullptr, N);
    k_gemm1<<<(N + 63) / 64, 256, 0, stream>>>(mean1, x, Wl1, Wr1, b1, h, N);
    k_gemm2<<<(N + 63) / 64, 256, 0, stream>>>(h, Wl2, Wr2, b2, mean1, zb, N);
    k_agg<<<(N + 3) / 4, 256, 0, stream>>>(mean1, off, csr, inv, zb, zb, N);
    k_decode<<<(P + 15) / 16, 256, 0, stream>>>(zb, eli, out, P);
}

// Round 2
// 338.956 us; speedup vs baseline: 1.5468x; 1.5468x over previous
//
#include <hip/hip_runtime.h>
#include <hip/hip_bf16.h>

// GNN link predictor: 2x SAGEConv(mean) + dot-product decode.
// Round 2 structure:
//   ELL adjacency (no count/scan kernels): pos = atomicAdd(deg[dst]) is both
//   degree count and slot index. Overflow (pos >= W) goes to a list handled by
//   an atomic-add fallback kernel (statistically empty for Poisson(16) deg).
//   Fill + agg are XCD-sliced: block b owns node range (b&7) assuming
//   round-robin blockIdx->XCD, so ELL slot writes stay in one XCD's L2.
//   1. memset deg, ovf_cnt
//   2. fill ELL (sliced)
//   3. mean1 = agg(x)/deg            [N x 64]   (+ overflow fixup)
//   4. h = relu([mean1|x] @ [Wl1;Wr1] + b1)     [N x 128]
//   5. p = h @ Wl2 ; zb = h @ Wr2 + b2          [N x 64] each
//   6. z = agg(p)/deg + zb  (into zb)           (+ overflow fixup)
//   7. out[k] = dot(z[a_k], z[b_k])             [P]

#define NSLICE 8

__global__ __launch_bounds__(256) void k_fill_ell(const int* __restrict__ ei, int E,
                                                  int N, int nps, int W,
                                                  int* __restrict__ deg,
                                                  int* __restrict__ ell,
                                                  int* __restrict__ ovf_idx,
                                                  int* __restrict__ ovf_cnt) {
    const int slice = blockIdx.x & (NSLICE - 1);
    const int chunk = blockIdx.x >> 3;
    const int nchunks = gridDim.x >> 3;
    const int ce = (E + nchunks - 1) / nchunks;
    const int lo = chunk * ce;
    const int hi = min(E, lo + ce);
    const int lo_node = slice * nps;
    const int hi_node = min(N, lo_node + nps);
    for (int e = lo + threadIdx.x; e < hi; e += 256) {
        int d = ei[E + e];
        if (d >= lo_node && d < hi_node) {
            int s = ei[e];
            int pos = atomicAdd(&deg[d], 1);
            if (pos < W) {
                ell[(size_t)d * W + pos] = s;
            } else {
                int oi = atomicAdd(ovf_cnt, 1);
                ovf_idx[oi] = e;
            }
        }
    }
}

// one 64-lane wave per node; lane = channel (64 channels); XCD-sliced mapping
__global__ __launch_bounds__(256) void k_agg_ell(const float* __restrict__ feat,
                                                 const int* __restrict__ deg,
                                                 const int* __restrict__ ell,
                                                 int W,
                                                 float* __restrict__ outp,
                                                 const float* __restrict__ addend,
                                                 int n, int nps) {
    const int slice = blockIdx.x & (NSLICE - 1);
    const int idx = blockIdx.x >> 3;
    const int wi = idx * 4 + (threadIdx.x >> 6);
    if (wi >= nps) return;
    const int node = slice * nps + wi;
    if (node >= n) return;
    const int lane = threadIdx.x & 63;
    const int dg = deg[node];
    const int cnt = min(dg, W);
    const int* row = ell + (size_t)node * W;
    float acc = 0.f;
    int j = 0;
    for (; j + 4 <= cnt; j += 4) {
        int s0 = row[j], s1 = row[j + 1], s2 = row[j + 2], s3 = row[j + 3];
        float a = feat[(size_t)s0 * 64 + lane];
        float b = feat[(size_t)s1 * 64 + lane];
        float c = feat[(size_t)s2 * 64 + lane];
        float d = feat[(size_t)s3 * 64 + lane];
        acc += a; acc += b; acc += c; acc += d;
    }
    for (; j < cnt; ++j) acc += feat[(size_t)row[j] * 64 + lane];
    float val = acc / (float)max(dg, 1);
    size_t o = (size_t)node * 64 + lane;
    if (addend) val += addend[o];
    outp[o] = val;
}

// fallback: overflow edges (pos >= W) added with scaled atomics (normally 0 work)
__global__ __launch_bounds__(64) void k_overflow(const float* __restrict__ feat,
                                                 const int* __restrict__ deg,
                                                 const int* __restrict__ ovf_idx,
                                                 const int* __restrict__ ovf_cnt,
                                                 const int* __restrict__ ei, int E,
                                                 float* __restrict__ outp) {
    const int cnt = *ovf_cnt;
    const int lane = threadIdx.x;
    for (int i = blockIdx.x; i < cnt; i += gridDim.x) {
        int e = ovf_idx[i];
        int d = ei[E + e];
        int s = ei[e];
        float sc = 1.0f / (float)max(deg[d], 1);
        atomicAdd(&outp[(size_t)d * 64 + lane], feat[(size_t)s * 64 + lane] * sc);
    }
}

// h = relu([mean1 | x] @ [W_l1 ; W_r1] + b1)   M x 128, K = 64+64
__global__ __launch_bounds__(256) void k_gemm1(const float* __restrict__ mean1,
                                               const float* __restrict__ x,
                                               const float* __restrict__ Wl,
                                               const float* __restrict__ Wr,
                                               const float* __restrict__ b1,
                                               float* __restrict__ h, int M) {
    __shared__ float As[16][68];
    __shared__ float Ws[16][128];
    const int t = threadIdx.x;
    const int row0 = blockIdx.x * 64;
    const int tm = t & 15, tn = t >> 4;
    float acc[4][8];
#pragma unroll
    for (int i = 0; i < 4; i++)
#pragma unroll
        for (int j = 0; j < 8; j++) acc[i][j] = 0.f;

    const int ar = row0 + (t >> 2);
    const int ak = (t & 3) * 4;
    for (int kk = 0; kk < 8; ++kk) {
        float4 av = make_float4(0.f, 0.f, 0.f, 0.f);
        int kg = kk * 16 + ak;
        if (ar < M) {
            const float* sp = (kg < 64) ? (mean1 + (size_t)ar * 64 + kg)
                                        : (x + (size_t)ar * 64 + (kg - 64));
            av = *(const float4*)sp;
        }
        int k0 = kk * 16 + (t >> 5), j0 = (t & 31) * 4;
        int k1 = k0 + 8;
        float4 wv0 = *(const float4*)((k0 < 64) ? (Wl + k0 * 128 + j0)
                                                : (Wr + (k0 - 64) * 128 + j0));
        float4 wv1 = *(const float4*)((k1 < 64) ? (Wl + k1 * 128 + j0)
                                                : (Wr + (k1 - 64) * 128 + j0));
        __syncthreads();
        int lr = t >> 2;
        As[ak + 0][lr] = av.x; As[ak + 1][lr] = av.y;
        As[ak + 2][lr] = av.z; As[ak + 3][lr] = av.w;
        *(float4*)&Ws[t >> 5][j0] = wv0;
        *(float4*)&Ws[(t >> 5) + 8][j0] = wv1;
        __syncthreads();
#pragma unroll
        for (int k = 0; k < 16; ++k) {
            float4 a4 = *(const float4*)&As[k][tm * 4];
            float4 w0 = *(const float4*)&Ws[k][tn * 8];
            float4 w1 = *(const float4*)&Ws[k][tn * 8 + 4];
            float a[4] = {a4.x, a4.y, a4.z, a4.w};
            float wv[8] = {w0.x, w0.y, w0.z, w0.w, w1.x, w1.y, w1.z, w1.w};
#pragma unroll
            for (int i = 0; i < 4; i++)
#pragma unroll
                for (int j = 0; j < 8; j++) acc[i][j] += a[i] * wv[j];
        }
    }
    float4 bv0 = *(const float4*)&b1[tn * 8];
    float4 bv1 = *(const float4*)&b1[tn * 8 + 4];
    float bb[8] = {bv0.x, bv0.y, bv0.z, bv0.w, bv1.x, bv1.y, bv1.z, bv1.w};
#pragma unroll
    for (int i = 0; i < 4; i++) {
        int r = row0 + tm * 4 + i;
        if (r < M) {
            float4 o0, o1;
            o0.x = fmaxf(acc[i][0] + bb[0], 0.f);
            o0.y = fmaxf(acc[i][1] + bb[1], 0.f);
            o0.z = fmaxf(acc[i][2] + bb[2], 0.f);
            o0.w = fmaxf(acc[i][3] + bb[3], 0.f);
            o1.x = fmaxf(acc[i][4] + bb[4], 0.f);
            o1.y = fmaxf(acc[i][5] + bb[5], 0.f);
            o1.z = fmaxf(acc[i][6] + bb[6], 0.f);
            o1.w = fmaxf(acc[i][7] + bb[7], 0.f);
            *(float4*)&h[(size_t)r * 128 + tn * 8] = o0;
            *(float4*)&h[(size_t)r * 128 + tn * 8 + 4] = o1;
        }
    }
}

// p = h @ W_l2 (cols 0..63) ; zb = h @ W_r2 + b2 (cols 64..127)   K=128
__global__ __launch_bounds__(256) void k_gemm2(const float* __restrict__ h,
                                               const float* __restrict__ Wl,
                                               const float* __restrict__ Wr,
                                               const float* __restrict__ b2,
                                               float* __restrict__ p,
                                               float* __restrict__ zb, int M) {
    __shared__ float As[16][68];
    __shared__ float Ws[16][128];
    const int t = threadIdx.x;
    const int row0 = blockIdx.x * 64;
    const int tm = t & 15, tn = t >> 4;
    float acc[4][8];
#pragma unroll
    for (int i = 0; i < 4; i++)
#pragma unroll
        for (int j = 0; j < 8; j++) acc[i][j] = 0.f;

    const int ar = row0 + (t >> 2);
    const int ak = (t & 3) * 4;
    for (int kk = 0; kk < 8; ++kk) {
        float4 av = make_float4(0.f, 0.f, 0.f, 0.f);
        int kg = kk * 16 + ak;
        if (ar < M) av = *(const float4*)(h + (size_t)ar * 128 + kg);
        int k0 = kk * 16 + (t >> 5), j0 = (t & 31) * 4;
        int k1 = k0 + 8;
        float4 wv0 = *(const float4*)((j0 < 64) ? (Wl + k0 * 64 + j0)
                                                : (Wr + k0 * 64 + (j0 - 64)));
        float4 wv1 = *(const float4*)((j0 < 64) ? (Wl + k1 * 64 + j0)
                                                : (Wr + k1 * 64 + (j0 - 64)));
        __syncthreads();
        int lr = t >> 2;
        As[ak + 0][lr] = av.x; As[ak + 1][lr] = av.y;
        As[ak + 2][lr] = av.z; As[ak + 3][lr] = av.w;
        *(float4*)&Ws[t >> 5][j0] = wv0;
        *(float4*)&Ws[(t >> 5) + 8][j0] = wv1;
        __syncthreads();
#pragma unroll
        for (int k = 0; k < 16; ++k) {
            float4 a4 = *(const float4*)&As[k][tm * 4];
            float4 w0 = *(const float4*)&Ws[k][tn * 8];
            float4 w1 = *(const float4*)&Ws[k][tn * 8 + 4];
            float a[4] = {a4.x, a4.y, a4.z, a4.w};
            float wv[8] = {w0.x, w0.y, w0.z, w0.w, w1.x, w1.y, w1.z, w1.w};
#pragma unroll
            for (int i = 0; i < 4; i++)
#pragma unroll
                for (int j = 0; j < 8; j++) acc[i][j] += a[i] * wv[j];
        }
    }
    int c = tn * 8;
    if (c < 64) {
#pragma unroll
        for (int i = 0; i < 4; i++) {
            int r = row0 + tm * 4 + i;
            if (r < M) {
                *(float4*)&p[(size_t)r * 64 + c] =
                    make_float4(acc[i][0], acc[i][1], acc[i][2], acc[i][3]);
                *(float4*)&p[(size_t)r * 64 + c + 4] =
                    make_float4(acc[i][4], acc[i][5], acc[i][6], acc[i][7]);
            }
        }
    } else {
        int cc = c - 64;
        float4 bv0 = *(const float4*)&b2[cc];
        float4 bv1 = *(const float4*)&b2[cc + 4];
#pragma unroll
        for (int i = 0; i < 4; i++) {
            int r = row0 + tm * 4 + i;
            if (r < M) {
                *(float4*)&zb[(size_t)r * 64 + cc] =
                    make_float4(acc[i][0] + bv0.x, acc[i][1] + bv0.y,
                                acc[i][2] + bv0.z, acc[i][3] + bv0.w);
                *(float4*)&zb[(size_t)r * 64 + cc + 4] =
                    make_float4(acc[i][4] + bv1.x, acc[i][5] + bv1.y,
                                acc[i][6] + bv1.z, acc[i][7] + bv1.w);
            }
        }
    }
}

// 16 lanes per pair; float4 loads; shfl_xor reduce
__global__ __launch_bounds__(256) void k_decode(const float* __restrict__ z,
                                                const int* __restrict__ eli,
                                                float* __restrict__ out, int P) {
    int t = threadIdx.x;
    int g = blockIdx.x * 16 + (t >> 4);
    int l = t & 15;
    if (g >= P) return;
    int a = eli[g];
    int b = eli[P + g];
    float4 va = *(const float4*)(z + (size_t)a * 64 + l * 4);
    float4 vb = *(const float4*)(z + (size_t)b * 64 + l * 4);
    float s = va.x * vb.x + va.y * vb.y + va.z * vb.z + va.w * vb.w;
    s += __shfl_xor(s, 1);
    s += __shfl_xor(s, 2);
    s += __shfl_xor(s, 4);
    s += __shfl_xor(s, 8);
    if (l == 0) out[g] = s;
}

extern "C" void kernel_launch(void* const* d_in, const int* in_sizes, int n_in,
                              void* d_out, int out_size, void* d_ws, size_t ws_size,
                              hipStream_t stream) {
    const float* x   = (const float*)d_in[0];
    const float* Wl1 = (const float*)d_in[1];
    const float* Wr1 = (const float*)d_in[2];
    const float* b1  = (const float*)d_in[3];
    const float* Wl2 = (const float*)d_in[4];
    const float* Wr2 = (const float*)d_in[5];
    const float* b2  = (const float*)d_in[6];
    const int* ei  = (const int*)d_in[7];
    const int* eli = (const int*)d_in[8];
    const int N = in_sizes[0] / 64;
    const int E = in_sizes[7] / 2;
    const int P = in_sizes[8] / 2;
    float* out = (float*)d_out;

    // pick ELL width by available workspace (W=64 covers Poisson(16) max-deg
    // ~45 with huge margin; smaller W just routes more edges to overflow path)
    auto need = [&](int W) -> size_t {
        size_t s = 0;
        auto al = [&](size_t b) { s += (b + 255) & ~(size_t)255; };
        al((size_t)N * 4);            // deg
        al(4);                        // ovf_cnt
        al((size_t)N * W * 4);        // ell
        al((size_t)E * 4);            // ovf_idx
        al((size_t)N * 64 * 4);       // mean1 / p
        al((size_t)N * 128 * 4);      // h
        al((size_t)N * 64 * 4);       // zb / z
        return s;
    };
    int W = 64;
    if (need(64) > ws_size) W = (need(32) <= ws_size) ? 32 : 16;

    char* w = (char*)d_ws;
    auto alloc = [&](size_t bytes) {
        char* pp = w;
        w += (bytes + 255) & ~(size_t)255;
        return pp;
    };
    int*   deg     = (int*)alloc((size_t)N * 4);
    int*   ovf_cnt = (int*)alloc(4);
    int*   ell     = (int*)alloc((size_t)N * W * 4);
    int*   ovf_idx = (int*)alloc((size_t)E * 4);
    float* mean1   = (float*)alloc((size_t)N * 64 * 4);  // reused as p
    float* h       = (float*)alloc((size_t)N * 128 * 4);
    float* zb      = (float*)alloc((size_t)N * 64 * 4);  // becomes z in-place

    const int nps = (N + NSLICE - 1) / NSLICE;  // nodes per XCD slice

    hipMemsetAsync(deg, 0, (size_t)N * 4, stream);
    hipMemsetAsync(ovf_cnt, 0, 4, stream);

    const int fill_chunks = 256;
    k_fill_ell<<<fill_chunks * NSLICE, 256, 0, stream>>>(ei, E, N, nps, W, deg, ell,
                                                         ovf_idx, ovf_cnt);

    const int agg_grid = NSLICE * ((nps + 3) / 4);
    k_agg_ell<<<agg_grid, 256, 0, stream>>>(x, deg, ell, W, mean1, nullptr, N, nps);
    k_overflow<<<128, 64, 0, stream>>>(x, deg, ovf_idx, ovf_cnt, ei, E, mean1);

    k_gemm1<<<(N + 63) / 64, 256, 0, stream>>>(mean1, x, Wl1, Wr1, b1, h, N);
    k_gemm2<<<(N + 63) / 64, 256, 0, stream>>>(h, Wl2, Wr2, b2, mean1, zb, N);

    k_agg_ell<<<agg_grid, 256, 0, stream>>>(mean1, deg, ell, W, zb, zb, N, nps);
    k_overflow<<<128, 64, 0, stream>>>(mean1, deg, ovf_idx, ovf_cnt, ei, E, zb);

    k_decode<<<(P + 15) / 16, 256, 0, stream>>>(zb, eli, out, P);
}